// Round 1
// baseline (415.547 us; speedup 1.0000x reference)
//
#include <hip/hip_runtime.h>
#include <hip/hip_bf16.h>

#define L_LAYERS 4
#define B_DIM 256
#define H_DIM 65536
#define KC 1024                    // K-chunk per block -> 64 splits per layer
#define BK 64                      // K per staging step (2 MFMA k-steps)
#define NKT (KC / BK)              // 16
#define NKZ (H_DIM / KC)           // 64
#define NSLICE (L_LAYERS * NKZ)    // 256 partial-Gram slices
#define LDSTR 72                   // shorts per LDS row (144 B: 16B-aligned, odd multiple of 4 dwords -> same conflict class as proven LDSTR=40)

using bf16x8_t = __attribute__((ext_vector_type(8))) short;   // MFMA A/B operand (4 VGPRs)
using shortx8  = __attribute__((ext_vector_type(8))) short;   // 16-byte LDS store
using shortx4  = __attribute__((ext_vector_type(4))) short;   // 8-byte global store
using floatx4  = __attribute__((ext_vector_type(4))) float;   // MFMA accumulator

__device__ __forceinline__ unsigned short f2bf(float f) {
    // round-to-nearest-even fp32 -> bf16 (finite inputs)
    unsigned u = __float_as_uint(f);
    return (unsigned short)((u + 0x7fffu + ((u >> 16) & 1u)) >> 16);
}

// One block per (layer, kz): reads 256 rows x KC floats EXACTLY ONCE (1x fetch),
// computes the full 256x256 Gram partial, stores it bf16 to its own slice.
// Slice is symmetric (A==B operand), so we store transposed -> acc's 4 contiguous
// row-values become one 8 B vector store.
__global__ __launch_bounds__(512, 2) void gram_kernel(const float* __restrict__ hs,
                                                      short* __restrict__ S) {
    __shared__ short lds[B_DIM * LDSTR];   // 256 x 72 shorts = 36 KB

    const int tid = threadIdx.x;
    const int bx  = blockIdx.x;            // 0..255
    const int l   = bx >> 6;
    const int kz  = bx & (NKZ - 1);

    const int wave = tid >> 6, lane = tid & 63;
    const int wm = wave >> 1;              // 0..3: 64-row strip
    const int wn = wave & 1;               // 0..1: 128-col strip
    const int mrow = lane & 15, quad = lane >> 4;

    // staging: thread t covers row r = t>>1, floats [h*32, h*32+32) of the BK=64 window
    const int r = tid >> 1;
    const int h = tid & 1;
    const float* gp = hs + ((size_t)l * B_DIM + r) * H_DIM + (size_t)kz * KC + h * 32;
    const int ldsw = r * LDSTR + h * 32;   // short units

    floatx4 acc[4][8];
#pragma unroll
    for (int i = 0; i < 4; ++i)
#pragma unroll
        for (int j = 0; j < 8; ++j) acc[i][j] = (floatx4)0.0f;

    // register prefetch of K-slice 0: 128 B contiguous per thread
    float4 pv[8];
#pragma unroll
    for (int q = 0; q < 8; ++q) pv[q] = *(const float4*)(gp + q * 4);

    for (int kt = 0; kt < NKT; ++kt) {
        // convert current slice to bf16 and stage to LDS
#pragma unroll
        for (int q = 0; q < 4; ++q) {
            shortx8 w;
            w[0] = (short)f2bf(pv[2 * q].x);     w[1] = (short)f2bf(pv[2 * q].y);
            w[2] = (short)f2bf(pv[2 * q].z);     w[3] = (short)f2bf(pv[2 * q].w);
            w[4] = (short)f2bf(pv[2 * q + 1].x); w[5] = (short)f2bf(pv[2 * q + 1].y);
            w[6] = (short)f2bf(pv[2 * q + 1].z); w[7] = (short)f2bf(pv[2 * q + 1].w);
            *(shortx8*)&lds[ldsw + q * 8] = w;   // previous iteration's trailing barrier protects this
        }

        // issue next slice's loads; they land during the MFMA phase
        if (kt < NKT - 1) {
            const float* gn = gp + (kt + 1) * BK;
#pragma unroll
            for (int q = 0; q < 8; ++q) pv[q] = *(const float4*)(gn + q * 4);
        }
        __syncthreads();

#pragma unroll
        for (int kk = 0; kk < 2; ++kk) {
            bf16x8_t af[4], bfv[8];
#pragma unroll
            for (int i = 0; i < 4; ++i)
                af[i] = *(const bf16x8_t*)&lds[(wm * 64 + i * 16 + mrow) * LDSTR + kk * 32 + quad * 8];
#pragma unroll
            for (int j = 0; j < 8; ++j)
                bfv[j] = *(const bf16x8_t*)&lds[(wn * 128 + j * 16 + mrow) * LDSTR + kk * 32 + quad * 8];
#pragma unroll
            for (int i = 0; i < 4; ++i)
#pragma unroll
                for (int j = 0; j < 8; ++j)
                    acc[i][j] = __builtin_amdgcn_mfma_f32_16x16x32_bf16(af[i], bfv[j], acc[i][j], 0, 0, 0);
        }
        __syncthreads();
    }

    // store this block's partial Gram (bf16, transposed == identical by symmetry)
    short* Ssl = S + (size_t)bx * (B_DIM * B_DIM);
#pragma unroll
    for (int i = 0; i < 4; ++i) {
        const int row0 = wm * 64 + i * 16 + quad * 4;
#pragma unroll
        for (int j = 0; j < 8; ++j) {
            const int col = wn * 128 + j * 16 + mrow;
            shortx4 v;
            v[0] = (short)f2bf(acc[i][j][0]);
            v[1] = (short)f2bf(acc[i][j][1]);
            v[2] = (short)f2bf(acc[i][j][2]);
            v[3] = (short)f2bf(acc[i][j][3]);
            *(shortx4*)&Ssl[(size_t)col * B_DIM + row0] = v;
        }
    }
}

// G[l,i,j] = sum over kz of bf16 S[(l*NKZ+kz), i, j] — pure streaming reduce.
// Each thread handles a column PAIR via one uint load (both bf16 halves unpacked free).
__global__ __launch_bounds__(128) void reduce_kernel(const short* __restrict__ S,
                                                     float* __restrict__ G) {
    const int li = blockIdx.x;             // l*256 + i
    const int j2 = threadIdx.x;            // 0..127: column pair
    const int l  = li >> 8;
    const int i  = li & 255;
    const unsigned* base = (const unsigned*)(S + ((size_t)l * NKZ) * (B_DIM * B_DIM) + i * B_DIM) + j2;
    float s0 = 0.0f, s1 = 0.0f;
#pragma unroll
    for (int kz = 0; kz < NKZ; ++kz) {
        const unsigned u = base[(size_t)kz * (B_DIM * B_DIM / 2)];
        s0 += __uint_as_float(u << 16);             // low bf16
        s1 += __uint_as_float(u & 0xffff0000u);     // high bf16
    }
    float2 out;
    out.x = s0;
    out.y = s1;
    *(float2*)(G + (size_t)li * B_DIM + 2 * j2) = out;
}

__global__ __launch_bounds__(256) void loss_kernel(const float* __restrict__ G,
                                                   const int* __restrict__ task,
                                                   float* __restrict__ out) {
    const int i = blockIdx.x, l = blockIdx.y, j = threadIdx.x;

    // block-uniform int64-vs-int32 detection for task_type (proven in prior session)
    __shared__ int s_odd_nz;
    if (j == 0) s_odd_nz = 0;
    __syncthreads();
    if (j < 128 && task[2 * j + 1] != 0) s_odd_nz = 1;
    __syncthreads();
    const bool is64 = (s_odd_nz == 0);

    const float* Gl = G + (size_t)l * B_DIM * B_DIM;
    const float gij = Gl[i * B_DIM + j];
    const float gii = Gl[i * B_DIM + i];
    const float gjj = Gl[j * B_DIM + j];
    const float nd  = gij * rsqrtf(gii) * rsqrtf(gjj);
    const float d2  = fmaxf(2.0f - 2.0f * nd, 0.0f);
    const float w   = __expf(-2.0f * d2);   // exp(-d2 / 0.5)

    const int ti = is64 ? task[2 * i] : task[i];
    const int tj = is64 ? task[2 * j] : task[j];
    const float pm = (ti == tj && i != j) ? 1.0f : 0.0f;

    float a = w * pm, b = w;
#pragma unroll
    for (int off = 32; off > 0; off >>= 1) {
        a += __shfl_down(a, off);
        b += __shfl_down(b, off);
    }
    __shared__ float sa[4], sb[4];
    const int wv = j >> 6, ln = j & 63;
    if (ln == 0) { sa[wv] = a; sb[wv] = b; }
    __syncthreads();
    if (j == 0) {
        const float A  = sa[0] + sa[1] + sa[2] + sa[3];
        const float Bb = sb[0] + sb[1] + sb[2] + sb[3];
        const float c  = -logf((A + 1e-8f) / (Bb + 1e-8f)) * (0.2f / 1024.0f);
        atomicAdd(out, c);
    }
}

extern "C" void kernel_launch(void* const* d_in, const int* in_sizes, int n_in,
                              void* d_out, int out_size, void* d_ws, size_t ws_size,
                              hipStream_t stream) {
    const float* hs   = (const float*)d_in[0];
    const int*   task = (const int*)d_in[1];
    float*       out  = (float*)d_out;

    short* S = (short*)d_ws;                              // 256 slices x 128 KB = 32 MB (bf16)
    float* G = (float*)(S + (size_t)NSLICE * (B_DIM * B_DIM));  // +1 MB fp32

    hipMemsetAsync(out, 0, sizeof(float), stream);

    gram_kernel<<<dim3(NSLICE), dim3(512), 0, stream>>>(hs, S);
    reduce_kernel<<<dim3(L_LAYERS * B_DIM), dim3(128), 0, stream>>>(S, G);
    loss_kernel<<<dim3(B_DIM, L_LAYERS), dim3(256), 0, stream>>>(G, task, out);
}